// Round 10
// baseline (113.849 us; speedup 1.0000x reference)
//
#include <hip/hip_runtime.h>

// PopulationCoding, round 21.
//  r20 post-mortem: frag-ordered staging worked (fused <42us, total 122->112.6).
//  Conflict count IDENTICAL r19/r20 (4,972,739) -> conflicts ~all from conv
//  byte-LUT (same spikes). Fused ~37us =~ conv-LDS 16 (1536 wave-reads/CU x
//  ~25cyc @ 6-way) + LIF-VALU ~4 + GEMM-LDS ~5 + tails.
//  r21: f16x4 nibble LUT. 6 x ds_read_b64 from 16x8B tables; 128B table =
//  32 banks exactly once -> same-entry lanes broadcast, ZERO conflicts.
//  ~48 cyc/t vs ~75. pk_add_f16 sums, relu+dot exact f32. Byte-LUT build
//  (3072 e) -> 96-entry f16 build (768B). Error ~1e-4 final (<< 5.9e-3).
//  GEMM/LIF/popcount/Itile = r20 verbatim.
// B=1024, IN=512, D=256, P=8, T=32. Output [1024,256] fp32.

constexpr int D_DIM   = 256;
constexpr int NTOT    = 2048;   // D*P
constexpr int T_STEPS = 32;

typedef _Float16 f16x8 __attribute__((ext_vector_type(8)));
typedef _Float16 half4 __attribute__((ext_vector_type(4)));
typedef float    f32x4 __attribute__((ext_vector_type(4)));
typedef ushort   ushort8 __attribute__((ext_vector_type(8)));

#define GLOBAL_AS __attribute__((address_space(1)))
#define LDS_AS    __attribute__((address_space(3)))

__device__ __forceinline__ void split_f16(float v, ushort& h, ushort& l) {
    const _Float16 hf = (_Float16)v;
    const _Float16 lf = (_Float16)((v - (float)hf) * 2048.0f);  // lo pre-scaled 2^11
    h = __builtin_bit_cast(ushort, hf);
    l = __builtin_bit_cast(ushort, lf);
}

// ------------------------------------------------- K0: split-f16 conversion
__device__ __forceinline__ void conv_x_body(const float* __restrict__ x,
                                            ushort* __restrict__ Ah,
                                            ushort* __restrict__ Al,
                                            int blk, int t)
{
    const int idx = (blk * 256 + t) * 8;
    float v[8];
    *reinterpret_cast<float4*>(v)     = *reinterpret_cast<const float4*>(x + idx);
    *reinterpret_cast<float4*>(v + 4) = *reinterpret_cast<const float4*>(x + idx + 4);
    __align__(16) ushort h[8], l[8];
#pragma unroll
    for (int j = 0; j < 8; ++j) split_f16(v[j], h[j], l[j]);
    *reinterpret_cast<ushort8*>(Ah + idx) = *reinterpret_cast<const ushort8*>(h);
    *reinterpret_cast<ushort8*>(Al + idx) = *reinterpret_cast<const ushort8*>(l);
}

__device__ __forceinline__ void conv_w_body(const float* __restrict__ Wp,
                                            ushort* __restrict__ Bh,
                                            ushort* __restrict__ Bl,
                                            float (*tile)[69],
                                            int ib, int t)
{
    const int k0 = (ib >> 5) * 64;          // 8 k-tiles
    const int c0 = (ib & 31) * 64;          // 32 col-tiles
    {
        const int r = t >> 2, cq = (t & 3) * 16;
#pragma unroll
        for (int j = 0; j < 4; ++j)
            *reinterpret_cast<float4*>(&tile[r][cq + j * 4]) =
                *reinterpret_cast<const float4*>(Wp + (size_t)(k0 + r) * NTOT + c0 + cq + j * 4);
    }
    __syncthreads();
    const int rr = t >> 2, kc2 = (t & 3) * 16;
    __align__(16) ushort h[16], l[16];
#pragma unroll
    for (int j = 0; j < 16; ++j) split_f16(tile[kc2 + j][rr], h[j], l[j]);
    ushort* dh = Bh + (size_t)(c0 + rr) * 512 + k0 + kc2;
    ushort* dl = Bl + (size_t)(c0 + rr) * 512 + k0 + kc2;
    *reinterpret_cast<ushort8*>(dh)     = *reinterpret_cast<const ushort8*>(h);
    *reinterpret_cast<ushort8*>(dh + 8) = *reinterpret_cast<const ushort8*>(h + 8);
    *reinterpret_cast<ushort8*>(dl)     = *reinterpret_cast<const ushort8*>(l);
    *reinterpret_cast<ushort8*>(dl + 8) = *reinterpret_cast<const ushort8*>(l + 8);
}

__global__ __launch_bounds__(256)
void popcode_prep(const float* __restrict__ x, const float* __restrict__ Wp,
                  ushort* __restrict__ Ah, ushort* __restrict__ Al,
                  ushort* __restrict__ Bh, ushort* __restrict__ Bl)
{
    __shared__ float tile[64][69];
    const int t = threadIdx.x;
    if (blockIdx.x < 256) conv_x_body(x, Ah, Al, blockIdx.x, t);
    else                  conv_w_body(Wp, Bh, Bl, tile, blockIdx.x - 256, t);
}

// ------------------------------------- K1: fused split-f16 MFMA GEMM + epi
// 512 blocks (XCD-swizzled), 256 threads (4 waves). Tile 64x64, BK=32.
// LDS (50560 B): [buf0 16K][buf1 16K][Itile 64x65 f32 16640][lut16 768][wlds 384]
//   per-buf planes: Ah 0, Al 4096, Bh 8192, Bl 12288 (4KB each).
//   Fragment-ordered: plane element (row=q*16+lr, kchunk lg) at
//   q*1024 + lane*16  (lane = lr + 16*lg).
//   lut16: [tap(3)][half(2)][nib(16)] x f16x4 channels, 8B entries.
__global__ __launch_bounds__(256)
void popcode_fused(const ushort* __restrict__ Ah_g, const ushort* __restrict__ Al_g,
                   const ushort* __restrict__ Bh_g, const ushort* __restrict__ Bl_g,
                   const float* __restrict__ bp, const float* __restrict__ thrs,
                   const float* __restrict__ rateW, const float* __restrict__ rateB,
                   const float* __restrict__ c1w, const float* __restrict__ c1b,
                   const float* __restrict__ c2w, const float* __restrict__ c2b,
                   const float* __restrict__ fus, float* __restrict__ out)
{
    __shared__ __align__(16) char smem[50560];
    LDS_AS char* lds0 = (LDS_AS char*)smem;

    const int tid  = threadIdx.x;
    const int w    = tid >> 6;          // wave id = staged plane id
    const int lane = tid & 63;

    // bijective XCD swizzle: 512 = 8 XCDs x 64 contiguous wgs.
    const int wg = (blockIdx.x & 7) * 64 + (blockIdx.x >> 3);
    const int b0 = (wg & 15) * 64;      // M tile (batch rows)
    const int c0 = (wg >> 4) * 64;      // N tile (neuron cols)

    const ushort* gbase = (w == 0) ? Ah_g : (w == 1) ? Al_g : (w == 2) ? Bh_g : Bl_g;
    const int     t0    = (w < 2) ? b0 : c0;
    const int     srow  = lane & 15;          // fragment-ordered staging
    const int     schk  = (lane >> 4) * 8;    // k-chunk, in halves

    const int wr = (w >> 1) * 32;       // quadrant row origin
    const int wc = (w & 1) * 32;        // quadrant col origin
    const int lr = lane & 15;
    const int lg = lane >> 4;

    const f32x4 zero = {0.f, 0.f, 0.f, 0.f};
    f32x4 acch[2][2] = {{zero, zero}, {zero, zero}};
    f32x4 accl[2][2] = {{zero, zero}, {zero, zero}};

    auto stage = [&](int buf, int kt) {
        const int koff = kt * 32 + schk;
#pragma unroll
        for (int i = 0; i < 4; ++i) {
            const ushort* src = gbase + (size_t)(t0 + srow + 16 * i) * 512 + koff;
            const int loff = __builtin_amdgcn_readfirstlane(buf * 16384 + w * 4096 + i * 1024);
            __builtin_amdgcn_global_load_lds((const GLOBAL_AS uint*)src,
                                             (LDS_AS uint*)(lds0 + loff), 16, 0, 0);
        }
    };

    auto compute = [&](int buf) {
        const int rbase = buf * 16384 + lane * 16;
        f16x8 ah[2], al[2], bh[2], bl[2];
#pragma unroll
        for (int m = 0; m < 2; ++m) {
            const int qa = (w >> 1) * 2 + m;          // row-group
            ah[m] = *reinterpret_cast<const f16x8*>(smem + rbase +        qa * 1024);
            al[m] = *reinterpret_cast<const f16x8*>(smem + rbase + 4096 + qa * 1024);
        }
#pragma unroll
        for (int n = 0; n < 2; ++n) {
            const int qb = (w & 1) * 2 + n;           // col-group
            bh[n] = *reinterpret_cast<const f16x8*>(smem + rbase +  8192 + qb * 1024);
            bl[n] = *reinterpret_cast<const f16x8*>(smem + rbase + 12288 + qb * 1024);
        }
#pragma unroll
        for (int m = 0; m < 2; ++m)
#pragma unroll
            for (int n = 0; n < 2; ++n) {
                acch[m][n] = __builtin_amdgcn_mfma_f32_16x16x32_f16(ah[m], bh[n], acch[m][n], 0, 0, 0);
                accl[m][n] = __builtin_amdgcn_mfma_f32_16x16x32_f16(al[m], bh[n], accl[m][n], 0, 0, 0);
                accl[m][n] = __builtin_amdgcn_mfma_f32_16x16x32_f16(ah[m], bl[n], accl[m][n], 0, 0, 0);
            }
    };

    // ---- prologue: wlds, first stage, f16 nibble-LUT build ----
    float* wlds  = (float*)(smem + 50176);
    half4* lut16 = (half4*)(smem + 49408);   // 96 entries x 8B
    if (tid < 96) wlds[tid] = c1w[tid];
    stage(0, 0);
    __syncthreads();                 // wlds visible; buf0 staged

    if (tid < 96) {
        const int k = tid >> 5;          // tap 0..2
        const int j = (tid >> 4) & 1;    // p-half
        const int n = tid & 15;          // nibble
        half4 hv;
#pragma unroll
        for (int c = 0; c < 4; ++c) {
            float v = (k == 1 && j == 0) ? c1b[c] : 0.f;  // fold conv1 bias once
#pragma unroll
            for (int p = 0; p < 4; ++p)
                v = fmaf((float)((n >> p) & 1), wlds[(c * 8 + j * 4 + p) * 3 + k], v);
            hv[c] = (_Float16)v;
        }
        lut16[tid] = hv;                 // entry e = k*32 + j*16 + n
    }

    // ---- GEMM k-loop (barriers make lut16 visible before epilogue) ----
    for (int kt = 0; kt < 16; ++kt) {
        if (kt < 15) stage((kt + 1) & 1, kt + 1);
        compute(kt & 1);
        __syncthreads();
    }

    // ---- acc -> Itile (C/D layout: col = lane&15, row = (lane>>4)*4 + v) ----
    float* it = (float*)(smem + 32768);  // [64][65]
    const float s = 1.0f / 2048.0f;
#pragma unroll
    for (int m = 0; m < 2; ++m)
#pragma unroll
        for (int n = 0; n < 2; ++n)
#pragma unroll
            for (int v = 0; v < 4; ++v)
                it[(wr + m * 16 + lg * 4 + v) * 65 + wc + n * 16 + lr] =
                    acch[m][n][v] + accl[m][n][v] * s;
    __syncthreads();

    // ---- uniform scalars ----
    float thrv[8];
#pragma unroll
    for (int p = 0; p < 8; ++p) thrv[p] = thrs[p];
    float w2c[4];
#pragma unroll
    for (int c = 0; c < 4; ++c) w2c[c] = c2w[c];
    const float f0 = fus[0], f1 = fus[1];
    const float fm = fmaxf(f0, f1);
    const float e0 = __expf(f0 - fm), e1 = __expf(f1 - fm);
    const float inv = 1.f / (e0 + e1);
    const float fw0 = e0 * inv, fw1 = e1 * inv;
    const float rb_ = rateB[0];
    const float bb2 = c2b[0];

    // ---- epilogue: 2 neurons per thread (row = tid>>2, d = tid&3, +4) ----
    const int row = tid >> 2;
    for (int n2 = 0; n2 < 2; ++n2) {
        const int dloc = (tid & 3) + n2 * 4;
        const int dg   = (c0 >> 3) + dloc;

        const float* ip = it + row * 65 + dloc * 8;
        float Iv[8], mem[8];
        bool  spk[8];
        {
            const float4 bv0 = *reinterpret_cast<const float4*>(bp + dg * 8);
            const float4 bv1 = *reinterpret_cast<const float4*>(bp + dg * 8 + 4);
            Iv[0] = ip[0] + bv0.x; Iv[1] = ip[1] + bv0.y;
            Iv[2] = ip[2] + bv0.z; Iv[3] = ip[3] + bv0.w;
            Iv[4] = ip[4] + bv1.x; Iv[5] = ip[5] + bv1.y;
            Iv[6] = ip[6] + bv1.z; Iv[7] = ip[7] + bv1.w;
        }
#pragma unroll
        for (int p = 0; p < 8; ++p) { mem[p] = 0.f; spk[p] = false; }

        // LIF, packing one byte per t (4 t per u32 word)
        unsigned wrd[8] = {0u, 0u, 0u, 0u, 0u, 0u, 0u, 0u};
#pragma unroll
        for (int t = 0; t < T_STEPS; ++t) {
            unsigned by = 0u;
#pragma unroll
            for (int p = 0; p < 8; ++p) {
                const float m2 = fmaf(0.95f, mem[p], Iv[p]);
                mem[p] = spk[p] ? (m2 - thrv[p]) : m2;
                spk[p] = mem[p] > thrv[p];
                by |= spk[p] ? (1u << p) : 0u;
            }
            wrd[t >> 2] |= by << (8 * (t & 3));
        }

        // rate branch: exact bit-plane popcount
        float rsum = 0.f;
#pragma unroll
        for (int p = 0; p < 8; ++p) {
            const unsigned m = 0x01010101u << p;
            int cnt = 0;
#pragma unroll
            for (int q = 0; q < 8; ++q) cnt += __popc(wrd[q] & m);
            rsum = fmaf((float)cnt, rateW[p], rsum);
        }

        // temporal conv: 6 conflict-free f16x4 nibble-LUT b64 reads per t
        auto getb = [&](int t) -> unsigned {
            return (wrd[t >> 2] >> (8 * (t & 3))) & 255u;
        };
        float tacc = 0.f;
        unsigned bp_ = 0u;
        unsigned bc_ = getb(0);
#pragma unroll
        for (int t = 0; t < T_STEPS; ++t) {
            const unsigned bn_ = (t < 31) ? getb(t + 1) : 0u;
            const half4 a0 = lut16[      (bp_ & 15)];
            const half4 a1 = lut16[16 + (bp_ >> 4)];
            const half4 b0 = lut16[32 + (bc_ & 15)];
            const half4 b1 = lut16[48 + (bc_ >> 4)];
            const half4 cv0 = lut16[64 + (bn_ & 15)];
            const half4 cv1 = lut16[80 + (bn_ >> 4)];
            const half4 hsum = (a0 + a1) + ((b0 + b1) + (cv0 + cv1));
            tacc = fmaf(fmaxf((float)hsum[0], 0.f), w2c[0], tacc);
            tacc = fmaf(fmaxf((float)hsum[1], 0.f), w2c[1], tacc);
            tacc = fmaf(fmaxf((float)hsum[2], 0.f), w2c[2], tacc);
            tacc = fmaf(fmaxf((float)hsum[3], 0.f), w2c[3], tacc);
            bp_ = bc_;
            bc_ = bn_;
        }

        const float rdec = rsum * (1.f / 32.f) + rb_;
        const float temp = tacc * (1.f / 32.f) + bb2;
        out[(b0 + row) * D_DIM + dg] = fw0 * rdec + fw1 * temp;
    }
}

extern "C" void kernel_launch(void* const* d_in, const int* in_sizes, int n_in,
                              void* d_out, int out_size, void* d_ws, size_t ws_size,
                              hipStream_t stream) {
    const float* x     = (const float*)d_in[0];
    const float* Wp    = (const float*)d_in[1];
    const float* bp    = (const float*)d_in[2];
    const float* thrs  = (const float*)d_in[3];
    const float* rateW = (const float*)d_in[4];
    const float* rateB = (const float*)d_in[5];
    const float* c1w   = (const float*)d_in[6];
    const float* c1b   = (const float*)d_in[7];
    const float* c2w   = (const float*)d_in[8];
    const float* c2b   = (const float*)d_in[9];
    const float* fus   = (const float*)d_in[10];
    float* out = (float*)d_out;
    float* ws  = (float*)d_ws;

    // ws layout: Ah[1024*512]u16 | Al | Bh[2048*512]u16 | Bl   (12 MB)
    ushort* Ah = reinterpret_cast<ushort*>(ws);
    ushort* Al = Ah + 1024 * 512;
    ushort* Bh = Al + 1024 * 512;
    ushort* Bl = Bh + 2048 * 512;

    popcode_prep<<<dim3(512), dim3(256), 0, stream>>>(x, Wp, Ah, Al, Bh, Bl);
    popcode_fused<<<dim3(512), dim3(256), 0, stream>>>(
        Ah, Al, Bh, Bl, bp, thrs, rateW, rateB, c1w, c1b, c2w, c2b, fus, out);
}

// Round 11
// 111.377 us; speedup vs baseline: 1.0222x; 1.0222x over previous
//
#include <hip/hip_runtime.h>

// PopulationCoding, round 22.
//  Ledger (fixed overhead ~70us calibrated from r19): r15 fused ~31.6,
//  r20 ~37.6, r21 ~38.8. Frag-ordered staging HURT (~6us): 16B/lane
//  scattered gload_lds sources vs r15's 64B 4-lane groups -> L2 waste.
//  r19 counters: VALUBusy 49.5%, Mfma 4.9%, HBM 3% at 2 blk/CU -> epi is
//  LATENCY-bound, not LDS/VALU-count-bound (explains 6 null conv variants).
//  r22: r15 staging (coalesced, conflicted ds_reads accepted) + r21 f16
//  nibble LUT + SINGLE staging buffer: LDS 50.5 -> 33.4KB -> 4 blocks/CU
//  (16 waves, 2x latency hiding in epi). k-loop: stage;sync;compute;sync.
// B=1024, IN=512, D=256, P=8, T=32. Output [1024,256] fp32.

constexpr int D_DIM   = 256;
constexpr int NTOT    = 2048;   // D*P
constexpr int T_STEPS = 32;

typedef _Float16 f16x8 __attribute__((ext_vector_type(8)));
typedef _Float16 half4 __attribute__((ext_vector_type(4)));
typedef float    f32x4 __attribute__((ext_vector_type(4)));
typedef ushort   ushort8 __attribute__((ext_vector_type(8)));

#define GLOBAL_AS __attribute__((address_space(1)))
#define LDS_AS    __attribute__((address_space(3)))

__device__ __forceinline__ void split_f16(float v, ushort& h, ushort& l) {
    const _Float16 hf = (_Float16)v;
    const _Float16 lf = (_Float16)((v - (float)hf) * 2048.0f);  // lo pre-scaled 2^11
    h = __builtin_bit_cast(ushort, hf);
    l = __builtin_bit_cast(ushort, lf);
}

// ------------------------------------------------- K0: split-f16 conversion
__device__ __forceinline__ void conv_x_body(const float* __restrict__ x,
                                            ushort* __restrict__ Ah,
                                            ushort* __restrict__ Al,
                                            int blk, int t)
{
    const int idx = (blk * 256 + t) * 8;
    float v[8];
    *reinterpret_cast<float4*>(v)     = *reinterpret_cast<const float4*>(x + idx);
    *reinterpret_cast<float4*>(v + 4) = *reinterpret_cast<const float4*>(x + idx + 4);
    __align__(16) ushort h[8], l[8];
#pragma unroll
    for (int j = 0; j < 8; ++j) split_f16(v[j], h[j], l[j]);
    *reinterpret_cast<ushort8*>(Ah + idx) = *reinterpret_cast<const ushort8*>(h);
    *reinterpret_cast<ushort8*>(Al + idx) = *reinterpret_cast<const ushort8*>(l);
}

__device__ __forceinline__ void conv_w_body(const float* __restrict__ Wp,
                                            ushort* __restrict__ Bh,
                                            ushort* __restrict__ Bl,
                                            float (*tile)[69],
                                            int ib, int t)
{
    const int k0 = (ib >> 5) * 64;          // 8 k-tiles
    const int c0 = (ib & 31) * 64;          // 32 col-tiles
    {
        const int r = t >> 2, cq = (t & 3) * 16;
#pragma unroll
        for (int j = 0; j < 4; ++j)
            *reinterpret_cast<float4*>(&tile[r][cq + j * 4]) =
                *reinterpret_cast<const float4*>(Wp + (size_t)(k0 + r) * NTOT + c0 + cq + j * 4);
    }
    __syncthreads();
    const int rr = t >> 2, kc2 = (t & 3) * 16;
    __align__(16) ushort h[16], l[16];
#pragma unroll
    for (int j = 0; j < 16; ++j) split_f16(tile[kc2 + j][rr], h[j], l[j]);
    ushort* dh = Bh + (size_t)(c0 + rr) * 512 + k0 + kc2;
    ushort* dl = Bl + (size_t)(c0 + rr) * 512 + k0 + kc2;
    *reinterpret_cast<ushort8*>(dh)     = *reinterpret_cast<const ushort8*>(h);
    *reinterpret_cast<ushort8*>(dh + 8) = *reinterpret_cast<const ushort8*>(h + 8);
    *reinterpret_cast<ushort8*>(dl)     = *reinterpret_cast<const ushort8*>(l);
    *reinterpret_cast<ushort8*>(dl + 8) = *reinterpret_cast<const ushort8*>(l + 8);
}

__global__ __launch_bounds__(256)
void popcode_prep(const float* __restrict__ x, const float* __restrict__ Wp,
                  ushort* __restrict__ Ah, ushort* __restrict__ Al,
                  ushort* __restrict__ Bh, ushort* __restrict__ Bl)
{
    __shared__ float tile[64][69];
    const int t = threadIdx.x;
    if (blockIdx.x < 256) conv_x_body(x, Ah, Al, blockIdx.x, t);
    else                  conv_w_body(Wp, Bh, Bl, tile, blockIdx.x - 256, t);
}

// ------------------------------------- K1: fused split-f16 MFMA GEMM + epi
// 512 blocks (XCD-swizzled), 256 threads (4 waves). Tile 64x64, BK=32.
// LDS (34176 B, 4 blocks/CU):
//   [planes 4x64x32 ushort = 16384][Itile 64x65 f32 = 16640]
//   [lut16 96x8B = 768][wlds 384]
//   planes row-major [plane][row][32 halves] (r15 layout): staging 64B
//   contiguous per 4 lanes (coalesced); ds_reads conflicted but hidden.
__global__ __launch_bounds__(256)
void popcode_fused(const ushort* __restrict__ Ah_g, const ushort* __restrict__ Al_g,
                   const ushort* __restrict__ Bh_g, const ushort* __restrict__ Bl_g,
                   const float* __restrict__ bp, const float* __restrict__ thrs,
                   const float* __restrict__ rateW, const float* __restrict__ rateB,
                   const float* __restrict__ c1w, const float* __restrict__ c1b,
                   const float* __restrict__ c2w, const float* __restrict__ c2b,
                   const float* __restrict__ fus, float* __restrict__ out)
{
    __shared__ __align__(16) char smem[34176];
    LDS_AS char* lds0 = (LDS_AS char*)smem;

    const int tid  = threadIdx.x;
    const int w    = tid >> 6;          // wave id = staged plane id
    const int lane = tid & 63;

    // bijective XCD swizzle: 512 = 8 XCDs x 64 contiguous wgs.
    const int wg = (blockIdx.x & 7) * 64 + (blockIdx.x >> 3);
    const int b0 = (wg & 15) * 64;      // M tile (batch rows)
    const int c0 = (wg >> 4) * 64;      // N tile (neuron cols)

    const ushort* gbase = (w == 0) ? Ah_g : (w == 1) ? Al_g : (w == 2) ? Bh_g : Bl_g;
    const int     t0    = (w < 2) ? b0 : c0;
    const int     srow  = lane >> 2;          // coalesced: 4 lanes = 64B of one row
    const int     schk  = (lane & 3) * 8;     // 16B chunk, in halves

    const int wr = (w >> 1) * 32;       // quadrant row origin
    const int wc = (w & 1) * 32;        // quadrant col origin
    const int lr = lane & 15;
    const int lg = lane >> 4;

    const f32x4 zero = {0.f, 0.f, 0.f, 0.f};
    f32x4 acch[2][2] = {{zero, zero}, {zero, zero}};
    f32x4 accl[2][2] = {{zero, zero}, {zero, zero}};

    auto stage = [&](int kt) {
        const int koff = kt * 32 + schk;
#pragma unroll
        for (int i = 0; i < 4; ++i) {
            const ushort* src = gbase + (size_t)(t0 + srow + 16 * i) * 512 + koff;
            const int loff = __builtin_amdgcn_readfirstlane(w * 4096 + i * 1024);
            __builtin_amdgcn_global_load_lds((const GLOBAL_AS uint*)src,
                                             (LDS_AS uint*)(lds0 + loff), 16, 0, 0);
        }
    };

    auto compute = [&]() {
        f16x8 ah[2], al[2], bh[2], bl[2];
#pragma unroll
        for (int m = 0; m < 2; ++m) {
            const int ro = (wr + m * 16 + lr) * 64 + lg * 16;
            ah[m] = *reinterpret_cast<const f16x8*>(smem +        ro);
            al[m] = *reinterpret_cast<const f16x8*>(smem + 4096 + ro);
        }
#pragma unroll
        for (int n = 0; n < 2; ++n) {
            const int co = (wc + n * 16 + lr) * 64 + lg * 16;
            bh[n] = *reinterpret_cast<const f16x8*>(smem +  8192 + co);
            bl[n] = *reinterpret_cast<const f16x8*>(smem + 12288 + co);
        }
#pragma unroll
        for (int m = 0; m < 2; ++m)
#pragma unroll
            for (int n = 0; n < 2; ++n) {
                acch[m][n] = __builtin_amdgcn_mfma_f32_16x16x32_f16(ah[m], bh[n], acch[m][n], 0, 0, 0);
                accl[m][n] = __builtin_amdgcn_mfma_f32_16x16x32_f16(al[m], bh[n], accl[m][n], 0, 0, 0);
                accl[m][n] = __builtin_amdgcn_mfma_f32_16x16x32_f16(ah[m], bl[n], accl[m][n], 0, 0, 0);
            }
    };

    // ---- prologue: wlds, first stage; f16 LUT build overlaps load wait ----
    float* wlds  = (float*)(smem + 33792);
    half4* lut16 = (half4*)(smem + 33024);   // 96 entries x 8B
    if (tid < 96) wlds[tid] = c1w[tid];
    stage(0);
    __syncthreads();                 // wlds visible; plane buf staged

    if (tid < 96) {
        const int k = tid >> 5;          // tap 0..2
        const int j = (tid >> 4) & 1;    // p-half
        const int n = tid & 15;          // nibble
        half4 hv;
#pragma unroll
        for (int c = 0; c < 4; ++c) {
            float v = (k == 1 && j == 0) ? c1b[c] : 0.f;  // fold conv1 bias once
#pragma unroll
            for (int p = 0; p < 4; ++p)
                v = fmaf((float)((n >> p) & 1), wlds[(c * 8 + j * 4 + p) * 3 + k], v);
            hv[c] = (_Float16)v;
        }
        lut16[tid] = hv;                 // entry e = k*32 + j*16 + n
    }

    // ---- GEMM k-loop (single buffer: stage;sync;compute;sync) ----
    for (int kt = 0; kt < 16; ++kt) {
        compute();
        __syncthreads();                 // all reads of this tile done
        if (kt < 15) {
            stage(kt + 1);
            __syncthreads();             // writes landed (vmcnt drained)
        }
    }

    // ---- acc -> Itile (C/D layout: col = lane&15, row = (lane>>4)*4 + v) ----
    float* it = (float*)(smem + 16384);  // [64][65]
    const float s = 1.0f / 2048.0f;
#pragma unroll
    for (int m = 0; m < 2; ++m)
#pragma unroll
        for (int n = 0; n < 2; ++n)
#pragma unroll
            for (int v = 0; v < 4; ++v)
                it[(wr + m * 16 + lg * 4 + v) * 65 + wc + n * 16 + lr] =
                    acch[m][n][v] + accl[m][n][v] * s;
    __syncthreads();

    // ---- uniform scalars ----
    float thrv[8];
#pragma unroll
    for (int p = 0; p < 8; ++p) thrv[p] = thrs[p];
    float w2c[4];
#pragma unroll
    for (int c = 0; c < 4; ++c) w2c[c] = c2w[c];
    const float f0 = fus[0], f1 = fus[1];
    const float fm = fmaxf(f0, f1);
    const float e0 = __expf(f0 - fm), e1 = __expf(f1 - fm);
    const float inv = 1.f / (e0 + e1);
    const float fw0 = e0 * inv, fw1 = e1 * inv;
    const float rb_ = rateB[0];
    const float bb2 = c2b[0];

    // ---- epilogue: 2 neurons per thread (row = tid>>2, d = tid&3, +4) ----
    const int row = tid >> 2;
    for (int n2 = 0; n2 < 2; ++n2) {
        const int dloc = (tid & 3) + n2 * 4;
        const int dg   = (c0 >> 3) + dloc;

        const float* ip = it + row * 65 + dloc * 8;
        float Iv[8], mem[8];
        bool  spk[8];
        {
            const float4 bv0 = *reinterpret_cast<const float4*>(bp + dg * 8);
            const float4 bv1 = *reinterpret_cast<const float4*>(bp + dg * 8 + 4);
            Iv[0] = ip[0] + bv0.x; Iv[1] = ip[1] + bv0.y;
            Iv[2] = ip[2] + bv0.z; Iv[3] = ip[3] + bv0.w;
            Iv[4] = ip[4] + bv1.x; Iv[5] = ip[5] + bv1.y;
            Iv[6] = ip[6] + bv1.z; Iv[7] = ip[7] + bv1.w;
        }
#pragma unroll
        for (int p = 0; p < 8; ++p) { mem[p] = 0.f; spk[p] = false; }

        // LIF, packing one byte per t (4 t per u32 word)
        unsigned wrd[8] = {0u, 0u, 0u, 0u, 0u, 0u, 0u, 0u};
#pragma unroll
        for (int t = 0; t < T_STEPS; ++t) {
            unsigned by = 0u;
#pragma unroll
            for (int p = 0; p < 8; ++p) {
                const float m2 = fmaf(0.95f, mem[p], Iv[p]);
                mem[p] = spk[p] ? (m2 - thrv[p]) : m2;
                spk[p] = mem[p] > thrv[p];
                by |= spk[p] ? (1u << p) : 0u;
            }
            wrd[t >> 2] |= by << (8 * (t & 3));
        }

        // rate branch: exact bit-plane popcount
        float rsum = 0.f;
#pragma unroll
        for (int p = 0; p < 8; ++p) {
            const unsigned m = 0x01010101u << p;
            int cnt = 0;
#pragma unroll
            for (int q = 0; q < 8; ++q) cnt += __popc(wrd[q] & m);
            rsum = fmaf((float)cnt, rateW[p], rsum);
        }

        // temporal conv: 6 conflict-free f16x4 nibble-LUT b64 reads per t
        auto getb = [&](int t) -> unsigned {
            return (wrd[t >> 2] >> (8 * (t & 3))) & 255u;
        };
        float tacc = 0.f;
        unsigned bp_ = 0u;
        unsigned bc_ = getb(0);
#pragma unroll
        for (int t = 0; t < T_STEPS; ++t) {
            const unsigned bn_ = (t < 31) ? getb(t + 1) : 0u;
            const half4 a0 = lut16[      (bp_ & 15)];
            const half4 a1 = lut16[16 + (bp_ >> 4)];
            const half4 b0 = lut16[32 + (bc_ & 15)];
            const half4 b1 = lut16[48 + (bc_ >> 4)];
            const half4 cv0 = lut16[64 + (bn_ & 15)];
            const half4 cv1 = lut16[80 + (bn_ >> 4)];
            const half4 hsum = (a0 + a1) + ((b0 + b1) + (cv0 + cv1));
            tacc = fmaf(fmaxf((float)hsum[0], 0.f), w2c[0], tacc);
            tacc = fmaf(fmaxf((float)hsum[1], 0.f), w2c[1], tacc);
            tacc = fmaf(fmaxf((float)hsum[2], 0.f), w2c[2], tacc);
            tacc = fmaf(fmaxf((float)hsum[3], 0.f), w2c[3], tacc);
            bp_ = bc_;
            bc_ = bn_;
        }

        const float rdec = rsum * (1.f / 32.f) + rb_;
        const float temp = tacc * (1.f / 32.f) + bb2;
        out[(b0 + row) * D_DIM + dg] = fw0 * rdec + fw1 * temp;
    }
}

extern "C" void kernel_launch(void* const* d_in, const int* in_sizes, int n_in,
                              void* d_out, int out_size, void* d_ws, size_t ws_size,
                              hipStream_t stream) {
    const float* x     = (const float*)d_in[0];
    const float* Wp    = (const float*)d_in[1];
    const float* bp    = (const float*)d_in[2];
    const float* thrs  = (const float*)d_in[3];
    const float* rateW = (const float*)d_in[4];
    const float* rateB = (const float*)d_in[5];
    const float* c1w   = (const float*)d_in[6];
    const float* c1b   = (const float*)d_in[7];
    const float* c2w   = (const float*)d_in[8];
    const float* c2b   = (const float*)d_in[9];
    const float* fus   = (const float*)d_in[10];
    float* out = (float*)d_out;
    float* ws  = (float*)d_ws;

    // ws layout: Ah[1024*512]u16 | Al | Bh[2048*512]u16 | Bl   (12 MB)
    ushort* Ah = reinterpret_cast<ushort*>(ws);
    ushort* Al = Ah + 1024 * 512;
    ushort* Bh = Al + 1024 * 512;
    ushort* Bl = Bh + 2048 * 512;

    popcode_prep<<<dim3(512), dim3(256), 0, stream>>>(x, Wp, Ah, Al, Bh, Bl);
    popcode_fused<<<dim3(512), dim3(256), 0, stream>>>(
        Ah, Al, Bh, Bl, bp, thrs, rateW, rateB, c1w, c1b, c2w, c2b, fus, out);
}